// Round 4
// baseline (186.363 us; speedup 1.0000x reference)
//
#include <hip/hip_runtime.h>

// MCLoss: mean |lap(gt) - lap(pr)| == mean |lap(gt - pr)|  (laplacian is linear).
// B=16, N=100000, M=9, nb[:,0]==i by construction.
//
// k1: tiled transpose+diff, float4 reads; pack d[i][b] = fp8x3(x,y,z)+pad in ONE
//     dword. Layout (N+1,16) dwords -> gather row = 64B = exactly 1 cache line.
//     Row N zeroed (absorbs idx==N); acc & done-counter zeroed.
// k2: 2 i's x 1 b per thread (round-2 winner shape: 3125 blocks — occupancy is
//     the limiter, round-3's 4-i version proved grid halving loses). 18 dword
//     gathers issued up front. Last block writes d_out (fused finalize).
//
// fp8 e4m3 RNE error analysis: sigma_E/sigma_L ~ 2e-2 -> relative bias ~2e-4,
// 50x under the 2% threshold.

#define NT 256
#define TI 64   // i's per k1 block (multiple of 4)

typedef float v2f __attribute__((ext_vector_type(2)));

__device__ __forceinline__ void unpack8(unsigned u, float& x, float& y, float& z) {
  v2f xy = __builtin_amdgcn_cvt_pk_f32_fp8((int)u, false);
  v2f zp = __builtin_amdgcn_cvt_pk_f32_fp8((int)u, true);
  x = xy[0]; y = xy[1]; z = zp[0];
}

__device__ __forceinline__ unsigned pack8(float x, float y, float z) {
  int u = __builtin_amdgcn_cvt_pk_fp8_f32(x, y, 0, false);
  u = __builtin_amdgcn_cvt_pk_fp8_f32(z, 0.0f, u, true);
  return (unsigned)u;
}

__global__ __launch_bounds__(NT) void k1_diff_pack(
    const float* __restrict__ gt, const float* __restrict__ pr,
    unsigned* __restrict__ dq, float* __restrict__ acc,
    unsigned* __restrict__ cnt, int N) {
  __shared__ float sm[16][3 * TI + 4];
  const int t = threadIdx.x;
  const int i0 = blockIdx.x * TI;
  const int ni = min(TI, N - i0);        // multiple of 4 (N%4==0, TI%4==0)
  const int nq = (3 * ni) >> 2;

  // Phase 1: 16 segments x 48 float4 (contiguous, aligned) -> LDS
#pragma unroll
  for (int k = 0; k < 3; k++) {
    int flat = t + k * NT;
    int seg = flat / 48;
    int q = flat - seg * 48;
    if (q < nq) {
      const float4* ga = (const float4*)(gt + ((size_t)seg * N + i0) * 3);
      const float4* pa = (const float4*)(pr + ((size_t)seg * N + i0) * 3);
      float4 a = ga[q];
      float4 p = pa[q];
      float4 df = make_float4(a.x - p.x, a.y - p.y, a.z - p.z, a.w - p.w);
      *(float4*)&sm[seg][q * 4] = df;
    }
  }
  __syncthreads();

  // Phase 2: coalesced 4B writes in transposed (i,b) order (64B per 16 lanes).
#pragma unroll
  for (int k = 0; k < (16 * TI) / NT; k++) {
    int el = t + k * NT;
    int il = el >> 4;
    int b = el & 15;
    if (il < ni) {
      float x = sm[b][il * 3 + 0];
      float y = sm[b][il * 3 + 1];
      float z = sm[b][il * 3 + 2];
      dq[(size_t)(i0 + il) * 16 + b] = pack8(x, y, z);
    }
  }

  if (blockIdx.x == 0) {
    if (t < 16) dq[(size_t)N * 16 + t] = 0u;   // pad row: fp8 zeros
    if (t == 16) *acc = 0.0f;
    if (t == 17) *cnt = 0u;
  }
}

__global__ __launch_bounds__(NT) void k2_lap_loss(
    const unsigned* __restrict__ dq, const int* __restrict__ nb,
    const float* __restrict__ nn, float* __restrict__ acc,
    unsigned* __restrict__ cnt, float* __restrict__ out,
    float scale, int N, int nblocks) {
  const int f = blockIdx.x * NT + threadIdx.x;
  const int g = f >> 4;          // i-pair
  const int b = f & 15;
  const int i0 = g * 2, i1 = i0 + 1;
  float s = 0.0f;

  if (i1 < N) {
    const int* rA = nb + (size_t)i0 * 9 + 1;
    const int* rB = rA + 9;
    int ia[8], ib[8];
#pragma unroll
    for (int j = 0; j < 8; j++) { ia[j] = rA[j]; ib[j] = rB[j]; }
    float wA = nn[i0], wB = nn[i1];

    // 18 independent 1-line gathers in flight
    unsigned cA = dq[(size_t)i0 * 16 + b];
    unsigned cB = dq[(size_t)i1 * 16 + b];
    unsigned vA[8], vB[8];
#pragma unroll
    for (int j = 0; j < 8; j++) vA[j] = dq[(size_t)ia[j] * 16 + b];
#pragma unroll
    for (int j = 0; j < 8; j++) vB[j] = dq[(size_t)ib[j] * 16 + b];

    float ax, ay, az;
    unpack8(cA, ax, ay, az);
    ax *= wA; ay *= wA; az *= wA;
#pragma unroll
    for (int j = 0; j < 8; j++) {
      float x, y, z; unpack8(vA[j], x, y, z);
      ax -= x; ay -= y; az -= z;
    }
    s = fabsf(ax) + fabsf(ay) + fabsf(az);

    float bx, by, bz;
    unpack8(cB, bx, by, bz);
    bx *= wB; by *= wB; bz *= wB;
#pragma unroll
    for (int j = 0; j < 8; j++) {
      float x, y, z; unpack8(vB[j], x, y, z);
      bx -= x; by -= y; bz -= z;
    }
    s += fabsf(bx) + fabsf(by) + fabsf(bz);
  } else if (i0 < N) {
    float wA = nn[i0];
    float ax, ay, az;
    unpack8(dq[(size_t)i0 * 16 + b], ax, ay, az);
    ax *= wA; ay *= wA; az *= wA;
    for (int j = 1; j < 9; j++) {
      int idx = nb[(size_t)i0 * 9 + j];
      float x, y, z; unpack8(dq[(size_t)idx * 16 + b], x, y, z);
      ax -= x; ay -= y; az -= z;
    }
    s = fabsf(ax) + fabsf(ay) + fabsf(az);
  }

  // wave (64) -> block -> one atomic; last block finalizes (fused k3)
#pragma unroll
  for (int off = 32; off > 0; off >>= 1) s += __shfl_down(s, off);
  __shared__ float sm[NT / 64];
  int lane = threadIdx.x & 63, wv = threadIdx.x >> 6;
  if (lane == 0) sm[wv] = s;
  __syncthreads();
  if (threadIdx.x == 0) {
    float tt = 0.0f;
#pragma unroll
    for (int k = 0; k < NT / 64; k++) tt += sm[k];
    atomicAdd(acc, tt);
    __threadfence();
    unsigned done = atomicAdd(cnt, 1u);
    if (done == (unsigned)(nblocks - 1)) {
      float total = atomicAdd(acc, 0.0f);
      out[0] = total * scale;
    }
  }
}

// ---------- fallback path (ws too small, K!=8, or N%4!=0) ----------
__global__ void k0_zero(float* __restrict__ acc) {
  if (threadIdx.x == 0) *acc = 0.0f;
}

__global__ __launch_bounds__(NT) void k2_direct(
    const float* __restrict__ gt, const float* __restrict__ pr,
    const int* __restrict__ nb, const float* __restrict__ nn,
    float* __restrict__ acc, int N, int K) {
  int u = blockIdx.x * NT + threadIdx.x;
  float s = 0.0f;
  if (u < 16 * N) {
    int b = u / N;
    int i = u - b * N;
    size_t cidx = ((size_t)b * N + i) * 3;
    float w = nn[i];
    float ax = (gt[cidx] - pr[cidx]) * w;
    float ay = (gt[cidx + 1] - pr[cidx + 1]) * w;
    float az = (gt[cidx + 2] - pr[cidx + 2]) * w;
    const int* row = nb + (size_t)i * (K + 1) + 1;
    for (int j = 0; j < K; j++) {
      int idx = row[j];
      if (idx < N) {
        size_t p = ((size_t)b * N + idx) * 3;
        ax -= (gt[p] - pr[p]);
        ay -= (gt[p + 1] - pr[p + 1]);
        az -= (gt[p + 2] - pr[p + 2]);
      }
    }
    s = fabsf(ax) + fabsf(ay) + fabsf(az);
  }
#pragma unroll
  for (int off = 32; off > 0; off >>= 1) s += __shfl_down(s, off);
  __shared__ float sm[NT / 64];
  int lane = threadIdx.x & 63, wv = threadIdx.x >> 6;
  if (lane == 0) sm[wv] = s;
  __syncthreads();
  if (threadIdx.x == 0) {
    float tt = 0.0f;
#pragma unroll
    for (int k = 0; k < NT / 64; k++) tt += sm[k];
    atomicAdd(acc, tt);
  }
}

__global__ void k3_finalize(const float* __restrict__ acc,
                            float* __restrict__ out, float scale) {
  if (threadIdx.x == 0) out[0] = acc[0] * scale;
}

extern "C" void kernel_launch(void* const* d_in, const int* in_sizes, int n_in,
                              void* d_out, int out_size, void* d_ws, size_t ws_size,
                              hipStream_t stream) {
  const float* gt = (const float*)d_in[0];
  const float* pr = (const float*)d_in[1];
  const int*   nb = (const int*)d_in[2];
  const float* nn = (const float*)d_in[3];
  int N = in_sizes[3];           // 100000
  int M = in_sizes[2] / N;       // 9
  int K = M - 1;                 // 8

  float scale = 1.0f / (16.0f * (float)N * 3.0f);
  size_t dbytes = (size_t)(N + 1) * 16 * sizeof(unsigned);
  size_t need = dbytes + 64;

  if (K == 8 && (N & 3) == 0 && ws_size >= need) {
    unsigned* dq  = (unsigned*)d_ws;
    float*    acc = (float*)((char*)d_ws + dbytes);
    unsigned* cnt = (unsigned*)(acc + 1);

    int b1 = (N + TI - 1) / TI;
    k1_diff_pack<<<b1, NT, 0, stream>>>(gt, pr, dq, acc, cnt, N);

    int groups = (N + 1) / 2;
    int b2 = ((size_t)groups * 16 + NT - 1) / NT;
    k2_lap_loss<<<b2, NT, 0, stream>>>(dq, nb, nn, acc, cnt, (float*)d_out,
                                       scale, N, b2);
  } else {
    float* acc = (float*)d_ws;
    k0_zero<<<1, 64, 0, stream>>>(acc);
    int b2 = (16 * N + NT - 1) / NT;
    k2_direct<<<b2, NT, 0, stream>>>(gt, pr, nb, nn, acc, N, K);
    k3_finalize<<<1, 64, 0, stream>>>(acc, (float*)d_out, scale);
  }
}